// Round 1
// baseline (431.264 us; speedup 1.0000x reference)
//
#include <hip/hip_runtime.h>
#include <hip/hip_bf16.h>
#include <stdint.h>

// ---------------------------------------------------------------------------
// MultiHeadAttention fused forward, bf16-MFMA pipeline.
// B=4, T=2048, D=1024, H=16, HD=64.  Input order: x, Wk, Wq, Wv, Wp, bp (fp32).
// Stages: cast -> QKV gemm_bt (MFMA 16x16x32 bf16) -> flash attn -> proj gemm.
// ---------------------------------------------------------------------------

typedef __bf16 bf16x8 __attribute__((ext_vector_type(8)));
typedef float floatx4 __attribute__((ext_vector_type(4)));
typedef unsigned short ushort_t;
typedef unsigned short ushortx8 __attribute__((ext_vector_type(8)));
typedef unsigned short ushortx4 __attribute__((ext_vector_type(4)));

#define MFMA16(a, b, c) __builtin_amdgcn_mfma_f32_16x16x32_bf16((a), (b), (c), 0, 0, 0)

static __device__ __forceinline__ ushort_t f2bfu(float f) {
  union { float f; unsigned u; } v; v.f = f;
  unsigned r = v.u + 0x7FFFu + ((v.u >> 16) & 1u);  // RNE
  return (ushort_t)(r >> 16);
}

// ---- fp32 -> bf16 cast, 4 elems/thread ----
__global__ void cvt_kernel(const float* __restrict__ in, ushort_t* __restrict__ out, int n4) {
  int i = blockIdx.x * blockDim.x + threadIdx.x;
  if (i >= n4) return;
  const float4 f = reinterpret_cast<const float4*>(in)[i];
  ushortx4 o;
  o[0] = f2bfu(f.x); o[1] = f2bfu(f.y); o[2] = f2bfu(f.z); o[3] = f2bfu(f.w);
  reinterpret_cast<ushortx4*>(out)[i] = o;
}

// ---------------------------------------------------------------------------
// QKV GEMM: C[m,n] = sum_k X[m,k] * W[n,k]   (M=8192, N=1024, K=1024)
// blockIdx.z selects W / output: 0->Wq->qbuf, 1->Wk->kbuf, 2->Wv->vtbuf.
// q/k stored [B,H,T,64]; v stored transposed [B,H,64,T].
// 128x128 tile per 256-thread block; 4 waves in 2x2; 64x64 per wave.
// ---------------------------------------------------------------------------
__global__ __launch_bounds__(256) void gemm_qkv(
    const ushort_t* __restrict__ X,
    const ushort_t* __restrict__ Wq, const ushort_t* __restrict__ Wk,
    const ushort_t* __restrict__ Wv,
    ushort_t* __restrict__ qb, ushort_t* __restrict__ kb, ushort_t* __restrict__ vtb)
{
  const int z = blockIdx.z;
  const ushort_t* Bm = (z == 0) ? Wq : (z == 1) ? Wk : Wv;
  __shared__ ushort_t Al[128 * 72];
  __shared__ ushort_t Bl[128 * 72];
  const int tid = threadIdx.x;
  const int w = tid >> 6, lane = tid & 63, g = lane >> 4, c = lane & 15;
  const int wm = w >> 1, wn = w & 1;
  const int m0 = blockIdx.x * 128, n0 = blockIdx.y * 128;

  floatx4 acc[4][4];
  const floatx4 zero4 = {0.f, 0.f, 0.f, 0.f};
#pragma unroll
  for (int i = 0; i < 4; ++i)
#pragma unroll
    for (int j = 0; j < 4; ++j) acc[i][j] = zero4;

  const int row_s = tid >> 3, ch = tid & 7;

  for (int k0 = 0; k0 < 1024; k0 += 64) {
#pragma unroll
    for (int p = 0; p < 4; ++p) {
      int row = row_s + p * 32;
      *reinterpret_cast<ushortx8*>(&Al[row * 72 + ch * 8]) =
          *reinterpret_cast<const ushortx8*>(&X[(m0 + row) * 1024 + k0 + ch * 8]);
      *reinterpret_cast<ushortx8*>(&Bl[row * 72 + ch * 8]) =
          *reinterpret_cast<const ushortx8*>(&Bm[(n0 + row) * 1024 + k0 + ch * 8]);
    }
    __syncthreads();
#pragma unroll
    for (int kk = 0; kk < 2; ++kk) {
      bf16x8 af[4], bfr[4];
#pragma unroll
      for (int i = 0; i < 4; ++i) {
        af[i]  = *reinterpret_cast<const bf16x8*>(&Al[(wm * 64 + i * 16 + c) * 72 + kk * 32 + g * 8]);
        bfr[i] = *reinterpret_cast<const bf16x8*>(&Bl[(wn * 64 + i * 16 + c) * 72 + kk * 32 + g * 8]);
      }
#pragma unroll
      for (int i = 0; i < 4; ++i)
#pragma unroll
        for (int j = 0; j < 4; ++j)
          acc[i][j] = MFMA16(af[i], bfr[j], acc[i][j]);
    }
    __syncthreads();
  }

  // Epilogue: C/D layout row = g*4+r, col = c within each 16x16 tile.
#pragma unroll
  for (int i = 0; i < 4; ++i) {
#pragma unroll
    for (int j = 0; j < 4; ++j) {
      const int mbase = m0 + wm * 64 + i * 16 + g * 4;
      const int n = n0 + wn * 64 + j * 16 + c;
      const int h = n >> 6, d = n & 63;
      if (z == 2) {
        // V transposed: vt[((bb*16+h)*64+d)*2048 + t], 4 consecutive t -> 8B store
        const int bb = mbase >> 11, t = mbase & 2047;
        ushortx4 pk;
#pragma unroll
        for (int r = 0; r < 4; ++r) pk[r] = f2bfu(acc[i][j][r]);
        *reinterpret_cast<ushortx4*>(&vtb[(size_t)((bb * 16 + h) * 64 + d) * 2048 + t]) = pk;
      } else {
        ushort_t* ob = (z == 0) ? qb : kb;
#pragma unroll
        for (int r = 0; r < 4; ++r) {
          const int m = mbase + r;
          const int bb = m >> 11, t = m & 2047;
          ob[(size_t)((bb * 16 + h) * 2048 + t) * 64 + d] = f2bfu(acc[i][j][r]);
        }
      }
    }
  }
}

// ---------------------------------------------------------------------------
// Flash attention (causal). One block = 64 Q rows of one (b,h); 4 waves x 16 rows.
// Key tiles of 64. S = Q K^T * 0.125 via MFMA; online softmax in registers
// (each lane owns 4 rows: row = g*4+r, stats reduced over 16-lane groups);
// P -> LDS -> A-operand-layout reload; O += P V via MFMA with V^T tiles.
// ---------------------------------------------------------------------------
__global__ __launch_bounds__(256) void attn_kernel(
    const ushort_t* __restrict__ qbuf, const ushort_t* __restrict__ kbuf,
    const ushort_t* __restrict__ vtbuf, ushort_t* __restrict__ obuf)
{
  const int qt = blockIdx.x, h = blockIdx.y, b = blockIdx.z;
  const int tid = threadIdx.x, w = tid >> 6, lane = tid & 63, g = lane >> 4, c = lane & 15;
  const int q0 = qt * 64;

  __shared__ ushort_t Kl[64 * 72];
  __shared__ ushort_t Vl[64 * 72];          // V^T tile: [d][key]
  __shared__ ushort_t Pl[4][16 * 72];       // per-wave P tile

  const size_t bh = (size_t)(b * 16 + h);
  const ushort_t* qbase = qbuf + (bh * 2048 + q0 + w * 16 + c) * 64;
  bf16x8 aq[2];
  aq[0] = *reinterpret_cast<const bf16x8*>(qbase + g * 8);
  aq[1] = *reinterpret_cast<const bf16x8*>(qbase + 32 + g * 8);

  float m_run[4], l_run[4];
  floatx4 oacc[4];
  const floatx4 zero4 = {0.f, 0.f, 0.f, 0.f};
#pragma unroll
  for (int r = 0; r < 4; ++r) { m_run[r] = -1e30f; l_run[r] = 0.f; }
#pragma unroll
  for (int td = 0; td < 4; ++td) oacc[td] = zero4;

  const ushort_t* kb_bh = kbuf + bh * 2048 * 64;
  const ushort_t* vt_bh = vtbuf + bh * 64 * 2048;
  const int row_s = tid >> 3, ch = tid & 7;

  for (int kt = 0; kt <= qt; ++kt) {
    const int key0 = kt * 64;
#pragma unroll
    for (int p = 0; p < 2; ++p) {
      const int row = row_s + p * 32;
      *reinterpret_cast<ushortx8*>(&Kl[row * 72 + ch * 8]) =
          *reinterpret_cast<const ushortx8*>(&kb_bh[(key0 + row) * 64 + ch * 8]);
      *reinterpret_cast<ushortx8*>(&Vl[row * 72 + ch * 8]) =
          *reinterpret_cast<const ushortx8*>(&vt_bh[row * 2048 + key0 + ch * 8]);
    }
    __syncthreads();

    // S = Q K^T * scale  (4 column tiles of 16 keys)
    float s[4][4];
#pragma unroll
    for (int t4 = 0; t4 < 4; ++t4) {
      floatx4 sa = zero4;
#pragma unroll
      for (int kk = 0; kk < 2; ++kk) {
        bf16x8 bk = *reinterpret_cast<const bf16x8*>(&Kl[(t4 * 16 + c) * 72 + kk * 32 + g * 8]);
        sa = MFMA16(aq[kk], bk, sa);
      }
#pragma unroll
      for (int r = 0; r < 4; ++r) s[t4][r] = sa[r] * 0.125f;
    }

    if (kt == qt) {  // causal mask on the diagonal tile
#pragma unroll
      for (int t4 = 0; t4 < 4; ++t4)
#pragma unroll
        for (int r = 0; r < 4; ++r) {
          const int key = key0 + t4 * 16 + c;
          const int q = q0 + w * 16 + g * 4 + r;
          if (key > q) s[t4][r] = -1e30f;
        }
    }

    float mnew[4], alpha[4], pv[4][4];
#pragma unroll
    for (int r = 0; r < 4; ++r) {
      float pm = fmaxf(fmaxf(s[0][r], s[1][r]), fmaxf(s[2][r], s[3][r]));
#pragma unroll
      for (int o = 1; o < 16; o <<= 1) pm = fmaxf(pm, __shfl_xor(pm, o, 64));
      mnew[r] = fmaxf(m_run[r], pm);
      alpha[r] = __expf(m_run[r] - mnew[r]);   // exp(-1e30-x) == 0, no NaN
    }
#pragma unroll
    for (int t4 = 0; t4 < 4; ++t4)
#pragma unroll
      for (int r = 0; r < 4; ++r) pv[t4][r] = __expf(s[t4][r] - mnew[r]);
#pragma unroll
    for (int r = 0; r < 4; ++r) {
      float ls = pv[0][r] + pv[1][r] + pv[2][r] + pv[3][r];
#pragma unroll
      for (int o = 1; o < 16; o <<= 1) ls += __shfl_xor(ls, o, 64);
      l_run[r] = l_run[r] * alpha[r] + ls;
      m_run[r] = mnew[r];
    }
#pragma unroll
    for (int td = 0; td < 4; ++td)
#pragma unroll
      for (int r = 0; r < 4; ++r) oacc[td][r] *= alpha[r];

    // P (C/D layout) -> LDS
#pragma unroll
    for (int t4 = 0; t4 < 4; ++t4)
#pragma unroll
      for (int r = 0; r < 4; ++r)
        Pl[w][(g * 4 + r) * 72 + t4 * 16 + c] = f2bfu(pv[t4][r]);
    __syncthreads();

    // O += P V : A-frag from Pl (m=c, k=g*8+j), B-frag from Vl (n=d, k=key)
#pragma unroll
    for (int td = 0; td < 4; ++td) {
#pragma unroll
      for (int kk = 0; kk < 2; ++kk) {
        bf16x8 ap = *reinterpret_cast<const bf16x8*>(&Pl[w][c * 72 + kk * 32 + g * 8]);
        bf16x8 bv = *reinterpret_cast<const bf16x8*>(&Vl[(td * 16 + c) * 72 + kk * 32 + g * 8]);
        oacc[td] = MFMA16(ap, bv, oacc[td]);
      }
    }
    __syncthreads();
  }

  // Epilogue: write O/l in [b, t, h, d] order (proj GEMM's A layout)
#pragma unroll
  for (int td = 0; td < 4; ++td)
#pragma unroll
    for (int r = 0; r < 4; ++r) {
      const int q = q0 + w * 16 + g * 4 + r;
      const int d = td * 16 + c;
      obuf[((size_t)(b * 2048 + q) * 16 + h) * 64 + d] = f2bfu(oacc[td][r] / l_run[r]);
    }
}

// ---------------------------------------------------------------------------
// Output projection: out[m,n] = sum_k O[m,k] * Wp[n,k] + bp[n], fp32 out.
// ---------------------------------------------------------------------------
__global__ __launch_bounds__(256) void gemm_proj(
    const ushort_t* __restrict__ A, const ushort_t* __restrict__ Wp,
    const float* __restrict__ bias, float* __restrict__ out)
{
  __shared__ ushort_t Al[128 * 72];
  __shared__ ushort_t Bl[128 * 72];
  const int tid = threadIdx.x;
  const int w = tid >> 6, lane = tid & 63, g = lane >> 4, c = lane & 15;
  const int wm = w >> 1, wn = w & 1;
  const int m0 = blockIdx.x * 128, n0 = blockIdx.y * 128;

  floatx4 acc[4][4];
  const floatx4 zero4 = {0.f, 0.f, 0.f, 0.f};
#pragma unroll
  for (int i = 0; i < 4; ++i)
#pragma unroll
    for (int j = 0; j < 4; ++j) acc[i][j] = zero4;

  const int row_s = tid >> 3, ch = tid & 7;

  for (int k0 = 0; k0 < 1024; k0 += 64) {
#pragma unroll
    for (int p = 0; p < 4; ++p) {
      int row = row_s + p * 32;
      *reinterpret_cast<ushortx8*>(&Al[row * 72 + ch * 8]) =
          *reinterpret_cast<const ushortx8*>(&A[(m0 + row) * 1024 + k0 + ch * 8]);
      *reinterpret_cast<ushortx8*>(&Bl[row * 72 + ch * 8]) =
          *reinterpret_cast<const ushortx8*>(&Wp[(n0 + row) * 1024 + k0 + ch * 8]);
    }
    __syncthreads();
#pragma unroll
    for (int kk = 0; kk < 2; ++kk) {
      bf16x8 af[4], bfr[4];
#pragma unroll
      for (int i = 0; i < 4; ++i) {
        af[i]  = *reinterpret_cast<const bf16x8*>(&Al[(wm * 64 + i * 16 + c) * 72 + kk * 32 + g * 8]);
        bfr[i] = *reinterpret_cast<const bf16x8*>(&Bl[(wn * 64 + i * 16 + c) * 72 + kk * 32 + g * 8]);
      }
#pragma unroll
      for (int i = 0; i < 4; ++i)
#pragma unroll
        for (int j = 0; j < 4; ++j)
          acc[i][j] = MFMA16(af[i], bfr[j], acc[i][j]);
    }
    __syncthreads();
  }

#pragma unroll
  for (int i = 0; i < 4; ++i) {
#pragma unroll
    for (int j = 0; j < 4; ++j) {
      const int n = n0 + wn * 64 + j * 16 + c;
      const float bv = bias[n];
#pragma unroll
      for (int r = 0; r < 4; ++r) {
        const int m = m0 + wm * 64 + i * 16 + g * 4 + r;
        out[(size_t)m * 1024 + n] = acc[i][j][r] + bv;
      }
    }
  }
}

extern "C" void kernel_launch(void* const* d_in, const int* in_sizes, int n_in,
                              void* d_out, int out_size, void* d_ws, size_t ws_size,
                              hipStream_t stream) {
  const float* x  = (const float*)d_in[0];
  const float* Wk = (const float*)d_in[1];   // NOTE input order: x, Wk, Wq, Wv, Wp, bp
  const float* Wq = (const float*)d_in[2];
  const float* Wv = (const float*)d_in[3];
  const float* Wp = (const float*)d_in[4];
  const float* bp = (const float*)d_in[5];
  float* out = (float*)d_out;

  char* ws = (char*)d_ws;
  const size_t SZ_X = (size_t)8192 * 1024 * 2;  // 16 MB bf16
  const size_t SZ_W = (size_t)1024 * 1024 * 2;  //  2 MB bf16
  ushort_t* xb    = (ushort_t*)ws;  ws += SZ_X;
  ushort_t* wkb   = (ushort_t*)ws;  ws += SZ_W;
  ushort_t* wqb   = (ushort_t*)ws;  ws += SZ_W;
  ushort_t* wvb   = (ushort_t*)ws;  ws += SZ_W;
  ushort_t* wpb   = (ushort_t*)ws;  ws += SZ_W;
  ushort_t* qbuf  = (ushort_t*)ws;  ws += SZ_X;
  ushort_t* kbuf  = (ushort_t*)ws;  ws += SZ_X;
  ushort_t* vtbuf = (ushort_t*)ws;  ws += SZ_X;
  ushort_t* obuf  = xb;  // x is consumed by gemm_qkv before attn writes obuf

  cvt_kernel<<<8192, 256, 0, stream>>>(x,  xb,  8192 * 1024 / 4);
  cvt_kernel<<<1024, 256, 0, stream>>>(Wk, wkb, 1024 * 1024 / 4);
  cvt_kernel<<<1024, 256, 0, stream>>>(Wq, wqb, 1024 * 1024 / 4);
  cvt_kernel<<<1024, 256, 0, stream>>>(Wv, wvb, 1024 * 1024 / 4);
  cvt_kernel<<<1024, 256, 0, stream>>>(Wp, wpb, 1024 * 1024 / 4);

  gemm_qkv<<<dim3(64, 8, 3), 256, 0, stream>>>(xb, wqb, wkb, wvb, qbuf, kbuf, vtbuf);
  attn_kernel<<<dim3(32, 16, 4), 256, 0, stream>>>(qbuf, kbuf, vtbuf, obuf);
  gemm_proj<<<dim3(64, 8), 256, 0, stream>>>(obuf, wpb, bp, out);
}